// Round 6
// baseline (77.532 us; speedup 1.0000x reference)
//
#include <hip/hip_runtime.h>

constexpr int DIN  = 256;
constexpr int DOUT = 32;
constexpr int ET   = 64;    // entities per GEMM block
constexpr int ZPT  = 25;    // float4 zero-stores per thread per zero block

typedef float vfloat4 __attribute__((ext_vector_type(4)));

// k1: ONE dispatch, two block roles (Bresenham-interleaved):
//  - zero blocks: 25 NT float4 stores each (fire-and-forget; drain at write BW)
//  - GEMM blocks: R4's proven double-buffered reg-prefetch GEMM -> relu -> ws
// Roles are per-block, so no divergence hazards; waves co-schedule on CUs.
__global__ __launch_bounds__(256)
void k1_zero_gemm(const float* __restrict__ emb,
                  const float* __restrict__ weight,
                  const float* __restrict__ bias,
                  float* __restrict__ out,
                  float* __restrict__ ws,
                  int nent, int zTotal4, int gb, int total)
{
    __shared__ float s_emb[ET][68];     // 17.4 KB
    __shared__ float s_w[64 * DOUT];    // 8 KB

    const int bid = blockIdx.x;
    const int tid = threadIdx.x;

    // Bresenham role split: gemm iff floor((bid+1)*gb/total) > floor(bid*gb/total)
    const long long p = (long long)bid * gb;
    const int  gid     = (int)(p / total);
    const bool is_gemm = (int)((p + gb) / total) > gid;

    if (!is_gemm) {
        // ---------------- zero role ----------------
        const int zid = bid - gid;              // zero blocks before bid = bid - gemm-before
        vfloat4* outv = (vfloat4*)out;
        const vfloat4 z = {0.f, 0.f, 0.f, 0.f};
        const int zbase = zid * (ZPT * 256) + tid;
        #pragma unroll
        for (int q = 0; q < ZPT; ++q) {
            int idx = zbase + q * 256;
            if (idx < zTotal4) __builtin_nontemporal_store(z, &outv[idx]);
        }
        return;                                  // stores drain in HW; dispatch-end fences
    }

    // ---------------- GEMM role (R4 enc_fused, epilogue -> ws) ----------------
    const int og = tid & 7;
    const int eg = tid >> 3;
    const int eb = gid * ET;

    float4 pe[4];
    float4 pw[2];
    #pragma unroll
    for (int r = 0; r < 4; ++r) {
        int f = (r << 8) + tid, row = f >> 4, col = (f & 15) << 2;
        int e = eb + row; if (e >= nent) e = nent - 1;
        pe[r] = *(const float4*)&emb[(size_t)e * DIN + col];
    }
    #pragma unroll
    for (int r = 0; r < 2; ++r)
        pw[r] = *(const float4*)&weight[(size_t)(((r << 8) + tid) << 2)];

    float a0x=0.f,a0y=0.f,a0z=0.f,a0w=0.f;
    float a1x=0.f,a1y=0.f,a1z=0.f,a1w=0.f;

    for (int t = 0; t < 4; ++t) {
        #pragma unroll
        for (int r = 0; r < 4; ++r) {
            int f = (r << 8) + tid;
            *(float4*)&s_emb[f >> 4][(f & 15) << 2] = pe[r];
        }
        #pragma unroll
        for (int r = 0; r < 2; ++r)
            *(float4*)&s_w[((r << 8) + tid) << 2] = pw[r];
        __syncthreads();

        if (t < 3) {
            const int kt = (t + 1) * 64;
            #pragma unroll
            for (int r = 0; r < 4; ++r) {
                int f = (r << 8) + tid, row = f >> 4, col = (f & 15) << 2;
                int e = eb + row; if (e >= nent) e = nent - 1;
                pe[r] = *(const float4*)&emb[(size_t)e * DIN + kt + col];
            }
            #pragma unroll
            for (int r = 0; r < 2; ++r)
                pw[r] = *(const float4*)&weight[(size_t)kt * DOUT + (((r << 8) + tid) << 2)];
        }

        #pragma unroll
        for (int k = 0; k < 64; k += 4) {
            float4 e0 = *(const float4*)&s_emb[eg][k];
            float4 e1 = *(const float4*)&s_emb[eg + 32][k];
            float4 w0 = *(const float4*)&s_w[(k + 0) * DOUT + og * 4];
            float4 w1 = *(const float4*)&s_w[(k + 1) * DOUT + og * 4];
            float4 w2 = *(const float4*)&s_w[(k + 2) * DOUT + og * 4];
            float4 w3 = *(const float4*)&s_w[(k + 3) * DOUT + og * 4];
            a0x += e0.x*w0.x + e0.y*w1.x + e0.z*w2.x + e0.w*w3.x;
            a0y += e0.x*w0.y + e0.y*w1.y + e0.z*w2.y + e0.w*w3.y;
            a0z += e0.x*w0.z + e0.y*w1.z + e0.z*w2.z + e0.w*w3.z;
            a0w += e0.x*w0.w + e0.y*w1.w + e0.z*w2.w + e0.w*w3.w;
            a1x += e1.x*w0.x + e1.y*w1.x + e1.z*w2.x + e1.w*w3.x;
            a1y += e1.x*w0.y + e1.y*w1.y + e1.z*w2.y + e1.w*w3.y;
            a1z += e1.x*w0.z + e1.y*w1.z + e1.z*w2.z + e1.w*w3.z;
            a1w += e1.x*w0.w + e1.y*w1.w + e1.z*w2.w + e1.w*w3.w;
        }
        __syncthreads();
    }

    const float4 bv = *(const float4*)&bias[og * 4];
    const int ent0 = eb + eg;
    if (ent0 < nent) {
        float4 r;
        r.x = fmaxf(a0x + bv.x, 0.f); r.y = fmaxf(a0y + bv.y, 0.f);
        r.z = fmaxf(a0z + bv.z, 0.f); r.w = fmaxf(a0w + bv.w, 0.f);
        *(float4*)&ws[(size_t)ent0 * DOUT + og * 4] = r;
    }
    const int ent1 = eb + eg + 32;
    if (ent1 < nent) {
        float4 r;
        r.x = fmaxf(a1x + bv.x, 0.f); r.y = fmaxf(a1y + bv.y, 0.f);
        r.z = fmaxf(a1z + bv.z, 0.f); r.w = fmaxf(a1w + bv.w, 0.f);
        *(float4*)&ws[(size_t)ent1 * DOUT + og * 4] = r;
    }
}

// k2: masked scatter-add of ws into the zeroed out (proven in R5)
__global__ __launch_bounds__(256)
void k2_scatter(const float* __restrict__ ws,
                const int* __restrict__ ex, const int* __restrict__ ey,
                const int* __restrict__ en, const int* __restrict__ pW,
                float* __restrict__ out, int N, int nent, int HW)
{
    const int idx = blockIdx.x * 256 + threadIdx.x;
    const int ent = idx >> 2;
    if (ent >= nent) return;
    const int b = ent / N, n = ent - b * N;
    if (n >= en[b]) return;
    const int cg = (idx & 3) * 8;
    const float4 v0 = *(const float4*)&ws[(size_t)ent * DOUT + cg];
    const float4 v1 = *(const float4*)&ws[(size_t)ent * DOUT + cg + 4];
    const int x = ex[ent], y = ey[ent];
    const int Wd = *pW;
    float* base = out + ((size_t)b * DOUT + cg) * (size_t)HW + (size_t)y * Wd + x;
    const float v[8] = {v0.x, v0.y, v0.z, v0.w, v1.x, v1.y, v1.z, v1.w};
    #pragma unroll
    for (int j = 0; j < 8; ++j)
        if (v[j] != 0.f) atomicAdd(base + (size_t)j * HW, v[j]);
}

// ---------------- fallback: memset + R4's proven fused kernel ----------------
constexpr int FET = 64, FKT = 64, FEP = FKT + 4;
__global__ __launch_bounds__(256)
void enc_fallback(const float* __restrict__ emb, const float* __restrict__ weight,
                  const float* __restrict__ bias, const int* __restrict__ ex,
                  const int* __restrict__ ey, const int* __restrict__ en,
                  const int* __restrict__ pW, float* __restrict__ out,
                  int N, int nent, int HW)
{
    __shared__ float s_emb[FET][FEP];
    __shared__ float s_w[FKT * DOUT];
    const int tid = threadIdx.x;
    const int og = tid & 7, eg = tid >> 3;
    const int eb = blockIdx.x * FET;
    float4 pe[4]; float4 pw[2];
    #pragma unroll
    for (int r = 0; r < 4; ++r) {
        int f = (r << 8) + tid, row = f >> 4, col = (f & 15) << 2;
        int e = eb + row; if (e >= nent) e = nent - 1;
        pe[r] = *(const float4*)&emb[(size_t)e * DIN + col];
    }
    #pragma unroll
    for (int r = 0; r < 2; ++r) pw[r] = *(const float4*)&weight[(size_t)(((r << 8) + tid) << 2)];
    float acc[2][4] = {{0,0,0,0},{0,0,0,0}};
    for (int t = 0; t < 4; ++t) {
        #pragma unroll
        for (int r = 0; r < 4; ++r) {
            int f = (r << 8) + tid;
            *(float4*)&s_emb[f >> 4][(f & 15) << 2] = pe[r];
        }
        #pragma unroll
        for (int r = 0; r < 2; ++r) *(float4*)&s_w[((r << 8) + tid) << 2] = pw[r];
        __syncthreads();
        if (t < 3) {
            const int kt = (t + 1) * FKT;
            #pragma unroll
            for (int r = 0; r < 4; ++r) {
                int f = (r << 8) + tid, row = f >> 4, col = (f & 15) << 2;
                int e = eb + row; if (e >= nent) e = nent - 1;
                pe[r] = *(const float4*)&emb[(size_t)e * DIN + kt + col];
            }
            #pragma unroll
            for (int r = 0; r < 2; ++r)
                pw[r] = *(const float4*)&weight[(size_t)kt * DOUT + (((r << 8) + tid) << 2)];
        }
        #pragma unroll
        for (int k = 0; k < FKT; k += 4) {
            float4 e0 = *(const float4*)&s_emb[eg][k];
            float4 e1 = *(const float4*)&s_emb[eg + 32][k];
            float4 w0 = *(const float4*)&s_w[(k + 0) * DOUT + og * 4];
            float4 w1 = *(const float4*)&s_w[(k + 1) * DOUT + og * 4];
            float4 w2 = *(const float4*)&s_w[(k + 2) * DOUT + og * 4];
            float4 w3 = *(const float4*)&s_w[(k + 3) * DOUT + og * 4];
            acc[0][0] += e0.x*w0.x + e0.y*w1.x + e0.z*w2.x + e0.w*w3.x;
            acc[0][1] += e0.x*w0.y + e0.y*w1.y + e0.z*w2.y + e0.w*w3.y;
            acc[0][2] += e0.x*w0.z + e0.y*w1.z + e0.z*w2.z + e0.w*w3.z;
            acc[0][3] += e0.x*w0.w + e0.y*w1.w + e0.z*w2.w + e0.w*w3.w;
            acc[1][0] += e1.x*w0.x + e1.y*w1.x + e1.z*w2.x + e1.w*w3.x;
            acc[1][1] += e1.x*w0.y + e1.y*w1.y + e1.z*w2.y + e1.w*w3.y;
            acc[1][2] += e1.x*w0.z + e1.y*w1.z + e1.z*w2.z + e1.w*w3.z;
            acc[1][3] += e1.x*w0.w + e1.y*w1.w + e1.z*w2.w + e1.w*w3.w;
        }
        __syncthreads();
    }
    const int W = *pW;
    const float4 bv = *(const float4*)&bias[og * 4];
    #pragma unroll
    for (int i = 0; i < 2; ++i) {
        int ent = eb + eg + i * 32;
        if (ent >= nent) continue;
        int b = ent / N, n = ent - b * N;
        if (n >= en[b]) continue;
        float* dst = out + ((size_t)b * DOUT + og * 4) * (size_t)HW
                         + (size_t)ey[ent] * W + ex[ent];
        float v0 = fmaxf(acc[i][0] + bv.x, 0.f);
        float v1 = fmaxf(acc[i][1] + bv.y, 0.f);
        float v2 = fmaxf(acc[i][2] + bv.z, 0.f);
        float v3 = fmaxf(acc[i][3] + bv.w, 0.f);
        if (v0 != 0.f) atomicAdd(dst + 0 * (size_t)HW, v0);
        if (v1 != 0.f) atomicAdd(dst + 1 * (size_t)HW, v1);
        if (v2 != 0.f) atomicAdd(dst + 2 * (size_t)HW, v2);
        if (v3 != 0.f) atomicAdd(dst + 3 * (size_t)HW, v3);
    }
}

extern "C" void kernel_launch(void* const* d_in, const int* in_sizes, int n_in,
                              void* d_out, int out_size, void* d_ws, size_t ws_size,
                              hipStream_t stream) {
    const float* emb    = (const float*)d_in[0];
    const float* weight = (const float*)d_in[1];
    const float* bias   = (const float*)d_in[2];
    const int*   ex     = (const int*)d_in[3];
    const int*   ey     = (const int*)d_in[4];
    const int*   en     = (const int*)d_in[5];
    const int*   pW     = (const int*)d_in[7];
    float*       out    = (float*)d_out;

    const int nent = in_sizes[3];          // B*N
    const int B    = in_sizes[5];
    const int N    = nent / B;
    const int HW   = (int)((size_t)out_size / ((size_t)B * DOUT));
    const int zTotal4 = out_size / 4;

    const int gb = (nent + ET - 1) / ET;                 // GEMM blocks
    const int zb = (zTotal4 + ZPT * 256 - 1) / (ZPT * 256); // zero blocks
    const int total = gb + zb;

    const bool fits = (ws_size >= (size_t)nent * DOUT * sizeof(float)) &&
                      (out_size % 4 == 0) &&
                      ((size_t)zb * ZPT * 256 >= (size_t)zTotal4);

    if (fits) {
        k1_zero_gemm<<<total, 256, 0, stream>>>(emb, weight, bias, out,
                                                (float*)d_ws, nent, zTotal4, gb, total);
        const int blocks2 = (nent * 4 + 255) / 256;
        k2_scatter<<<blocks2, 256, 0, stream>>>((const float*)d_ws, ex, ey, en, pW,
                                                out, N, nent, HW);
    } else {
        (void)hipMemsetAsync(d_out, 0, (size_t)out_size * sizeof(float), stream);
        const int blocks = (nent + FET - 1) / FET;
        enc_fallback<<<blocks, 256, 0, stream>>>(emb, weight, bias, ex, ey, en, pW,
                                                 out, N, nent, HW);
    }
}

// Round 7
// 57.547 us; speedup vs baseline: 1.3473x; 1.3473x over previous
//
#include <hip/hip_runtime.h>
#include <stdint.h>

constexpr int DIN  = 256;
constexpr int DOUT = 32;

typedef float f32x4  __attribute__((ext_vector_type(4)));
typedef short bf16x8 __attribute__((ext_vector_type(8)));

// ws layout (bytes):
//   [0,      16384)  wfrag_hi : bf16 [8 ktiles][2 colhalves][64 lanes][8]
//   [16384,  32768)  wfrag_lo : same layout (residual bf16)
//   [32768,  32768+4*nent) destpk : int per entity (out base offset, or -1 masked)

__device__ __forceinline__ uint16_t f2bf(float f, float& back) {
    uint32_t u = __builtin_bit_cast(uint32_t, f);
    uint32_t r = (u + 0x7fffu + ((u >> 16) & 1u)) >> 16;   // RNE
    back = __builtin_bit_cast(float, r << 16);
    return (uint16_t)r;
}

// prep: blocks [0,4) build W fragments (hi/lo bf16, MFMA B layout);
//       blocks [4, 4+ceil(nent/256)) pack per-entity dest offset + mask.
__global__ __launch_bounds__(256)
void k_prep(const float* __restrict__ weight,
            const int* __restrict__ ex, const int* __restrict__ ey,
            const int* __restrict__ en, const int* __restrict__ pW,
            uint16_t* __restrict__ wfh, uint16_t* __restrict__ wfl,
            int* __restrict__ destpk,
            int N, int nent, int HW)
{
    const int bid = blockIdx.x, tid = threadIdx.x;
    if (bid < 4) {
        const int id   = bid * 256 + tid;        // 0..1023 = (t, h, lane)
        const int t    = id >> 7;
        const int h    = (id >> 6) & 1;
        const int lane = id & 63;
        const int kb   = t * 32 + (lane >> 4) * 8;
        const int col  = h * 16 + (lane & 15);
        const int off  = ((t * 2 + h) * 64 + lane) * 8;
        #pragma unroll
        for (int j = 0; j < 8; ++j) {
            float w = weight[(size_t)(kb + j) * DOUT + col];
            float back; uint16_t hi = f2bf(w, back);
            float resid = w - back;
            float b2;  uint16_t lo = f2bf(resid, b2);
            wfh[off + j] = hi;
            wfl[off + j] = lo;
        }
    } else {
        const int e = (bid - 4) * 256 + tid;
        if (e < nent) {
            const int b = e / N, n = e - b * N;
            const int W = *pW;
            destpk[e] = (n < en[b]) ? (b * DOUT * HW + ey[e] * W + ex[e]) : -1;
        }
    }
}

// gemm+scatter: no LDS, no barriers. wave = 16 entities x 32 outs.
// A-frag: lane reads emb[row = lane&15][k = t*32 + (lane>>4)*8 + j] directly
// from global (fp32) and splits to bf16 hi/lo. B-frag: preconverted (same
// (lane,j)->k map, so any k-slot permutation cancels). 6 MFMAs per k-tile:
// hi*hi + lo*hi + hi*lo (lo*lo ~2^-18, dropped).
__global__ __launch_bounds__(256)
void k_gemm_scatter(const float* __restrict__ emb,
                    const float* __restrict__ bias,
                    const uint16_t* __restrict__ wfh,
                    const uint16_t* __restrict__ wfl,
                    const int* __restrict__ destpk,
                    float* __restrict__ out,
                    int nent, int HW)
{
    const int tid  = threadIdx.x;
    const int lane = tid & 63;
    const int wv   = tid >> 6;
    const int eb   = blockIdx.x * 64 + wv * 16;
    const int row  = lane & 15;
    const int kg   = lane >> 4;

    int e = eb + row; if (e >= nent) e = nent - 1;
    const float* erow = emb + (size_t)e * DIN + kg * 8;

    f32x4 acc0 = {0.f, 0.f, 0.f, 0.f};
    f32x4 acc1 = {0.f, 0.f, 0.f, 0.f};

    #pragma unroll
    for (int t = 0; t < 8; ++t) {
        const float4 a0 = *(const float4*)(erow + t * 32);
        const float4 a1 = *(const float4*)(erow + t * 32 + 4);
        const float af[8] = {a0.x, a0.y, a0.z, a0.w, a1.x, a1.y, a1.z, a1.w};
        bf16x8 ahi, alo;
        #pragma unroll
        for (int j = 0; j < 8; ++j) {
            float back; uint16_t h = f2bf(af[j], back);
            float resid = af[j] - back;
            float b2;  uint16_t l = f2bf(resid, b2);
            ahi[j] = (short)h;
            alo[j] = (short)l;
        }
        const int fo = (t * 2) * 64 + lane;       // colhalf 0; +64 = colhalf 1
        const bf16x8 bh0 = *(const bf16x8*)&wfh[fo * 8];
        const bf16x8 bh1 = *(const bf16x8*)&wfh[(fo + 64) * 8];
        const bf16x8 bl0 = *(const bf16x8*)&wfl[fo * 8];
        const bf16x8 bl1 = *(const bf16x8*)&wfl[(fo + 64) * 8];
        acc0 = __builtin_amdgcn_mfma_f32_16x16x32_bf16(ahi, bh0, acc0, 0, 0, 0);
        acc1 = __builtin_amdgcn_mfma_f32_16x16x32_bf16(ahi, bh1, acc1, 0, 0, 0);
        acc0 = __builtin_amdgcn_mfma_f32_16x16x32_bf16(alo, bh0, acc0, 0, 0, 0);
        acc1 = __builtin_amdgcn_mfma_f32_16x16x32_bf16(alo, bh1, acc1, 0, 0, 0);
        acc0 = __builtin_amdgcn_mfma_f32_16x16x32_bf16(ahi, bl0, acc0, 0, 0, 0);
        acc1 = __builtin_amdgcn_mfma_f32_16x16x32_bf16(ahi, bl1, acc1, 0, 0, 0);
    }

    // C/D layout (m89/m91 verified): col = lane&15, row = (lane>>4)*4 + reg
    const int c0 = lane & 15, c1 = c0 + 16;
    const float b0 = bias[c0], b1 = bias[c1];
    #pragma unroll
    for (int r = 0; r < 4; ++r) {
        const int ent = eb + (lane >> 4) * 4 + r;
        if (ent >= nent) continue;
        const int d = destpk[ent];
        if (d < 0) continue;
        const float v0 = fmaxf(acc0[r] + b0, 0.f);
        const float v1 = fmaxf(acc1[r] + b1, 0.f);
        if (v0 != 0.f) atomicAdd(out + d + c0 * HW, v0);
        if (v1 != 0.f) atomicAdd(out + d + c1 * HW, v1);
    }
}

// ---------------- fallback: memset + R4's proven fused kernel ----------------
constexpr int FET = 64, FKT = 64, FEP = FKT + 4;
__global__ __launch_bounds__(256)
void enc_fallback(const float* __restrict__ emb, const float* __restrict__ weight,
                  const float* __restrict__ bias, const int* __restrict__ ex,
                  const int* __restrict__ ey, const int* __restrict__ en,
                  const int* __restrict__ pW, float* __restrict__ out,
                  int N, int nent, int HW)
{
    __shared__ float s_emb[FET][FEP];
    __shared__ float s_w[FKT * DOUT];
    const int tid = threadIdx.x;
    const int og = tid & 7, eg = tid >> 3;
    const int eb = blockIdx.x * FET;
    float4 pe[4]; float4 pw[2];
    #pragma unroll
    for (int r = 0; r < 4; ++r) {
        int f = (r << 8) + tid, rw = f >> 4, col = (f & 15) << 2;
        int e = eb + rw; if (e >= nent) e = nent - 1;
        pe[r] = *(const float4*)&emb[(size_t)e * DIN + col];
    }
    #pragma unroll
    for (int r = 0; r < 2; ++r) pw[r] = *(const float4*)&weight[(size_t)(((r << 8) + tid) << 2)];
    float acc[2][4] = {{0,0,0,0},{0,0,0,0}};
    for (int t = 0; t < 4; ++t) {
        #pragma unroll
        for (int r = 0; r < 4; ++r) {
            int f = (r << 8) + tid;
            *(float4*)&s_emb[f >> 4][(f & 15) << 2] = pe[r];
        }
        #pragma unroll
        for (int r = 0; r < 2; ++r) *(float4*)&s_w[((r << 8) + tid) << 2] = pw[r];
        __syncthreads();
        if (t < 3) {
            const int kt = (t + 1) * FKT;
            #pragma unroll
            for (int r = 0; r < 4; ++r) {
                int f = (r << 8) + tid, rw = f >> 4, col = (f & 15) << 2;
                int e = eb + rw; if (e >= nent) e = nent - 1;
                pe[r] = *(const float4*)&emb[(size_t)e * DIN + kt + col];
            }
            #pragma unroll
            for (int r = 0; r < 2; ++r)
                pw[r] = *(const float4*)&weight[(size_t)kt * DOUT + (((r << 8) + tid) << 2)];
        }
        #pragma unroll
        for (int k = 0; k < FKT; k += 4) {
            float4 e0 = *(const float4*)&s_emb[eg][k];
            float4 e1 = *(const float4*)&s_emb[eg + 32][k];
            float4 w0 = *(const float4*)&s_w[(k + 0) * DOUT + og * 4];
            float4 w1 = *(const float4*)&s_w[(k + 1) * DOUT + og * 4];
            float4 w2 = *(const float4*)&s_w[(k + 2) * DOUT + og * 4];
            float4 w3 = *(const float4*)&s_w[(k + 3) * DOUT + og * 4];
            acc[0][0] += e0.x*w0.x + e0.y*w1.x + e0.z*w2.x + e0.w*w3.x;
            acc[0][1] += e0.x*w0.y + e0.y*w1.y + e0.z*w2.y + e0.w*w3.y;
            acc[0][2] += e0.x*w0.z + e0.y*w1.z + e0.z*w2.z + e0.w*w3.z;
            acc[0][3] += e0.x*w0.w + e0.y*w1.w + e0.z*w2.w + e0.w*w3.w;
            acc[1][0] += e1.x*w0.x + e1.y*w1.x + e1.z*w2.x + e1.w*w3.x;
            acc[1][1] += e1.x*w0.y + e1.y*w1.y + e1.z*w2.y + e1.w*w3.y;
            acc[1][2] += e1.x*w0.z + e1.y*w1.z + e1.z*w2.z + e1.w*w3.z;
            acc[1][3] += e1.x*w0.w + e1.y*w1.w + e1.z*w2.w + e1.w*w3.w;
        }
        __syncthreads();
    }
    const int W = *pW;
    const float4 bv = *(const float4*)&bias[og * 4];
    #pragma unroll
    for (int i = 0; i < 2; ++i) {
        int ent = eb + eg + i * 32;
        if (ent >= nent) continue;
        int b = ent / N, n = ent - b * N;
        if (n >= en[b]) continue;
        float* dst = out + ((size_t)b * DOUT + og * 4) * (size_t)HW
                         + (size_t)ey[ent] * W + ex[ent];
        float v0 = fmaxf(acc[i][0] + bv.x, 0.f);
        float v1 = fmaxf(acc[i][1] + bv.y, 0.f);
        float v2 = fmaxf(acc[i][2] + bv.z, 0.f);
        float v3 = fmaxf(acc[i][3] + bv.w, 0.f);
        if (v0 != 0.f) atomicAdd(dst + 0 * (size_t)HW, v0);
        if (v1 != 0.f) atomicAdd(dst + 1 * (size_t)HW, v1);
        if (v2 != 0.f) atomicAdd(dst + 2 * (size_t)HW, v2);
        if (v3 != 0.f) atomicAdd(dst + 3 * (size_t)HW, v3);
    }
}

extern "C" void kernel_launch(void* const* d_in, const int* in_sizes, int n_in,
                              void* d_out, int out_size, void* d_ws, size_t ws_size,
                              hipStream_t stream) {
    const float* emb    = (const float*)d_in[0];
    const float* weight = (const float*)d_in[1];
    const float* bias   = (const float*)d_in[2];
    const int*   ex     = (const int*)d_in[3];
    const int*   ey     = (const int*)d_in[4];
    const int*   en     = (const int*)d_in[5];
    const int*   pW     = (const int*)d_in[7];
    float*       out    = (float*)d_out;

    const int nent = in_sizes[3];          // B*N
    const int B    = in_sizes[5];
    const int N    = nent / B;
    const int HW   = (int)((size_t)out_size / ((size_t)B * DOUT));

    uint16_t* wfh    = (uint16_t*)d_ws;
    uint16_t* wfl    = (uint16_t*)((char*)d_ws + 16384);
    int*      destpk = (int*)((char*)d_ws + 32768);

    const size_t ws_need = 32768 + (size_t)nent * sizeof(int);
    const bool fits = (ws_size >= ws_need);

    if (fits) {
        const int prep_blocks = 4 + (nent + 255) / 256;
        k_prep<<<prep_blocks, 256, 0, stream>>>(weight, ex, ey, en, pW,
                                                wfh, wfl, destpk, N, nent, HW);
        (void)hipMemsetAsync(d_out, 0, (size_t)out_size * sizeof(float), stream);
        const int gblocks = (nent + 63) / 64;
        k_gemm_scatter<<<gblocks, 256, 0, stream>>>(emb, bias, wfh, wfl, destpk,
                                                    out, nent, HW);
    } else {
        (void)hipMemsetAsync(d_out, 0, (size_t)out_size * sizeof(float), stream);
        const int blocks = (nent + FET - 1) / FET;
        enc_fallback<<<blocks, 256, 0, stream>>>(emb, weight, bias, ex, ey, en, pW,
                                                 out, N, nent, HW);
    }
}